// Round 15
// baseline (267.188 us; speedup 1.0000x reference)
//
#include <hip/hip_runtime.h>
#include <hip/hip_bf16.h>
#include <math.h>

#define IN_CHN 128
#define OUT_CHN 128
#define KD 192
#define TM 64                  // edges per tile
#define HXP 136                // hx row stride in ushorts (272B, 16B-aligned)

typedef __bf16 bf16x8 __attribute__((ext_vector_type(8)));
typedef float f32x4 __attribute__((ext_vector_type(4)));

static __device__ __forceinline__ unsigned short f2b(float f) {
    return __builtin_bit_cast(unsigned short, (__bf16)f);   // RNE
}
static __device__ __forceinline__ float b2f(unsigned short b) {
    return __uint_as_float(((unsigned int)b) << 16);
}
static __device__ __forceinline__ float fast_tanh(float x) {
    float e = __expf(2.0f * x);
    return 1.0f - 2.0f * __builtin_amdgcn_rcpf(e + 1.0f);
}

// async global->LDS, 16B per lane; LDS dest wave-uniform base + lane*16
#define GLL16(gsrc, ldst) \
    __builtin_amdgcn_global_load_lds( \
        (const __attribute__((address_space(1))) unsigned int*)(gsrc), \
        (__attribute__((address_space(3))) unsigned int*)(ldst), 16, 0, 0)

// light barrier: cross-wave LDS visibility WITHOUT draining vmcnt (keeps
// in-flight global_load_lds alive across it)
#define LDS_BARRIER() do { \
    asm volatile("s_waitcnt lgkmcnt(0)" ::: "memory"); \
    __builtin_amdgcn_s_barrier(); \
    __builtin_amdgcn_sched_barrier(0); \
} while (0)

// ---------------- x -> bf16 + degree count + side init (one pass) ----------------
// deg must be zeroed (memsetAsync) before this kernel.

__global__ __launch_bounds__(256) void cvt_cnt(const float* __restrict__ x,
    unsigned short* __restrict__ xb, const int* __restrict__ ei,
    int* __restrict__ deg, int* __restrict__ side_node,
    long long n8, int E, int nb)
{
    long long i = (long long)blockIdx.x * 256 + threadIdx.x;
    if (i < n8) {
        const float4* src = (const float4*)(x + i * 8);
        float4 v0 = src[0], v1 = src[1];
        ushort4 p0 = { f2b(v0.x), f2b(v0.y), f2b(v0.z), f2b(v0.w) };
        ushort4 p1 = { f2b(v1.x), f2b(v1.y), f2b(v1.z), f2b(v1.w) };
        *(ushort4*)(xb + i * 8)     = p0;
        *(ushort4*)(xb + i * 8 + 4) = p1;
    }
    int t = (int)i;
    if (t < E) atomicAdd(&deg[ei[E + t]], 1);
    if (t < nb) side_node[t] = -1;
}

// ---------------- CSR build ----------------

static __device__ __forceinline__ int wave_incl_scan(int v, int lane) {
    #pragma unroll
    for (int off = 1; off < 64; off <<= 1) {
        int t = __shfl_up(v, off);
        if (lane >= off) v += t;
    }
    return v;
}

__global__ __launch_bounds__(256) void scan_local(const int* __restrict__ deg,
    int* __restrict__ offs, int* __restrict__ partial, int Nn)
{
    __shared__ int wsum[4];
    int tid = threadIdx.x, lane = tid & 63, wid = tid >> 6;
    int i = blockIdx.x * 256 + tid;
    int v = (i < Nn) ? deg[i] : 0;
    int incl = wave_incl_scan(v, lane);
    if (lane == 63) wsum[wid] = incl;
    __syncthreads();
    int wpre = 0;
    for (int w = 0; w < wid; ++w) wpre += wsum[w];
    if (i < Nn) offs[i] = wpre + incl - v;
    if (tid == 255) partial[blockIdx.x] = wpre + incl;
}

// per-block: sum partials[0..b) directly (nblk <= 256), add, write cursor
__global__ __launch_bounds__(256) void finalize2(int* __restrict__ offs,
    const int* __restrict__ partial, int* __restrict__ cursor,
    int Nn, int E, int nblk)
{
    __shared__ int wsum[4];
    int b = blockIdx.x, tid = threadIdx.x, lane = tid & 63, wid = tid >> 6;
    int v = (tid < b && tid < nblk) ? partial[tid] : 0;
    #pragma unroll
    for (int off = 32; off > 0; off >>= 1) v += __shfl_xor(v, off);
    if (lane == 0) wsum[wid] = v;
    __syncthreads();
    int bp = wsum[0] + wsum[1] + wsum[2] + wsum[3];
    int i = b * 256 + tid;
    if (i < Nn) {
        int o = offs[i] + bp;
        offs[i] = o; cursor[i] = o;
        if (i == Nn - 1) offs[Nn] = E;   // sentinel
    }
}

// scatter (src, t) into CSR-permuted order as one 8B store
__global__ __launch_bounds__(256) void fill_perm(const int* __restrict__ ei,
    const float* __restrict__ et, int* __restrict__ cursor,
    uint2* __restrict__ mt, int E)
{
    int e = blockIdx.x * 256 + threadIdx.x;
    if (e < E) {
        int d = ei[E + e];
        int pos = atomicAdd(&cursor[d], 1);
        mt[pos] = make_uint2((unsigned)ei[e], __float_as_uint(et[e]));
    }
}

// ---------------- fused MFMA GEMM + softmax aggregation ----------------
// R14 structure, NEW wave decomposition: 8 waves = 2 edge-halves x 4
// channel-quarters (was 1x8). Each wave computes its 32 edges x 32 ch slice
// -> reads only HALF the xs/te tile: MFMA-feed ds_read_b128 24 -> 12 per
// wave per tile (DS pipe was the binding resource at ~95us). W frags double
// to Wf[6][2] (48 VGPR) but stay well under the 4-waves/SIMD cap.
// Schedule (2 barriers), swizzles, staging, agg, tail: identical to R14.

__device__ __forceinline__ void load_meta(const uint2* __restrict__ mt,
    int tile, int E, int rbase, int g, int trow, int sv[2], float& tsv)
{
    int e0 = tile * TM;
    #pragma unroll
    for (int i = 0; i < 2; ++i) {
        int e = e0 + rbase + i * 4 + g;
        sv[i] = (int)mt[e < E ? e : E - 1].x;
    }
    int el = e0 + trow;
    tsv = __uint_as_float(mt[el < E ? el : E - 1].y);
}

__global__ __launch_bounds__(512) void gemm_fused(
    const unsigned short* __restrict__ xb, const uint2* __restrict__ mt,
    const int* __restrict__ offs,
    const float* __restrict__ freqs, const float* __restrict__ lw,
    const float* __restrict__ lb, const float* __restrict__ attn,
    float* __restrict__ out, float* __restrict__ den_g,
    int* __restrict__ side_node, float* __restrict__ side_den,
    float* __restrict__ side_val,
    int E, int Nn, int n_tiles, int kq, int kr)
{
    __shared__ unsigned short xs[2][TM][128];   // 32768 B x tile (dbuf)
    __shared__ unsigned short te[2][TM * 64];   // 16384 B te tile (dbuf, swizzled)
    __shared__ unsigned short hx[TM * HXP];     // 17408 B h tile
    __shared__ float exs[2][TM];                //   512 B alpha accumulators (dbuf)

    const int b    = blockIdx.x;
    const int t0   = b * kq + min(b, kr);
    const int cnt  = kq + (b < kr ? 1 : 0);
    if (cnt <= 0 || t0 >= n_tiles) return;
    const int tend = min(t0 + cnt, n_tiles);
    const int be0  = t0 * TM;
    const int bend = min(tend * TM, E);

    const int tid  = threadIdx.x;
    const int lane = tid & 63;
    const int wv   = tid >> 6;          // wave 0..7
    const int c16  = lane & 15;
    const int g    = lane >> 4;         // 0..3
    const int we   = wv & 1;            // edge half: rows [we*32, we*32+32)
    const int wc   = wv >> 1;           // channel quarter: [wc*32, wc*32+32)
    const int cbase = wc * 32;
    const int ebase = we * 32;
    const int rbase = wv * 8;           // gll staging row base (unchanged)
    const int trow  = tid >> 3;         // te row 0..63
    const int tpart = tid & 7;          // te part (0-3 sin, 4-7 cos)
    const int sub  = lane >> 4;         // agg: edge subgroup 0..3
    const int chl  = lane & 15;         // agg: channel lane (8 ch)

    // W frags in registers: lane's row(ch) = cbase + nf*16 + c16; k = kk*32+g*8+j
    bf16x8 Wf[6][2];
    #pragma unroll
    for (int kk = 0; kk < 6; ++kk)
        #pragma unroll
        for (int nf = 0; nf < 2; ++nf) {
            const float* wp = lw + (size_t)(cbase + nf * 16 + c16) * KD + kk * 32 + g * 8;
            float4 v0 = *(const float4*)wp;
            float4 v1 = *(const float4*)(wp + 4);
            bf16x8 bb;
            bb[0] = (__bf16)v0.x; bb[1] = (__bf16)v0.y; bb[2] = (__bf16)v0.z; bb[3] = (__bf16)v0.w;
            bb[4] = (__bf16)v1.x; bb[5] = (__bf16)v1.y; bb[6] = (__bf16)v1.z; bb[7] = (__bf16)v1.w;
            Wf[kk][nf] = bb;
        }
    f32x4 bias_v[2], attn_v[2];
    #pragma unroll
    for (int nf = 0; nf < 2; ++nf) {
        bias_v[nf] = *(const f32x4*)(lb   + cbase + nf * 16 + g * 4);
        attn_v[nf] = *(const f32x4*)(attn + cbase + nf * 16 + g * 4);
    }

    const float coff = (tpart >= 4) ? 1.5707963267948966f : 0.0f;  // cos = sin(x+pi/2)
    float frv[8];
    #pragma unroll
    for (int j = 0; j < 8; ++j) frv[j] = freqs[(tpart & 3) * 8 + j] * 6.283185307179586f;

    // ---- first node of block: binary search offs (uniform across threads) ----
    int n0;
    {
        int lo = 0, hi = Nn;
        while (lo + 1 < hi) {
            int mid = (lo + hi) >> 1;
            if (offs[mid] <= be0) lo = mid; else hi = mid;
        }
        n0 = lo;
    }
    int cur_node = n0 + ((wv - (n0 & 7)) & 7);
    float a[8];
    #pragma unroll
    for (int q = 0; q < 8; ++q) a[q] = 0.0f;
    float den = 0.0f;

    // ---- prologue: meta(t0), gll(t0)->xs[0], te(t0)->te[0], exs[0]=0, meta(t1) ----
    float ts_nxt;
    int sv_nxt[2];
    {
        int sv0[2]; float ts0;
        load_meta(mt, t0, E, rbase, g, trow, sv0, ts0);
        #pragma unroll
        for (int i = 0; i < 2; ++i) {
            const int rlo = (rbase + i * 4 + g) & 15;
            const unsigned short* gsrc = xb + (size_t)sv0[i] * IN_CHN + ((c16 ^ rlo) * 8);
            GLL16(gsrc, &xs[0][rbase + i * 4][0]);
        }
        // te(t0) -> te[0]
        float v[8];
        #pragma unroll
        for (int j = 0; j < 8; ++j)
            v[j] = __sinf(ts0 * frv[j] + coff);
        unsigned short* tr = &te[0][trow * 64];
        int slot = (tpart ^ (trow & 7)) * 8;
        *(ushort4*)(tr + slot)     = (ushort4){ f2b(v[0]), f2b(v[1]), f2b(v[2]), f2b(v[3]) };
        *(ushort4*)(tr + slot + 4) = (ushort4){ f2b(v[4]), f2b(v[5]), f2b(v[6]), f2b(v[7]) };
        if (tid < TM) exs[0][tid] = 0.0f;

        int t1 = t0 + 1;
        load_meta(mt, t1 < tend ? t1 : tend - 1, E, rbase, g, trow, sv_nxt, ts_nxt);
    }

    int cur = 0;
    for (int tile = t0; tile < tend; ++tile) {
        const int e0 = tile * TM;
        const int e1 = e0 + TM;

        // ---- compute + write te(t+1) -> te[cur^1] (pre-A; safe via C(t-1)) ----
        {
            float v[8];
            #pragma unroll
            for (int j = 0; j < 8; ++j)
                v[j] = __sinf(ts_nxt * frv[j] + coff);
            unsigned short* tr = &te[cur ^ 1][trow * 64];
            int slot = (tpart ^ (trow & 7)) * 8;
            *(ushort4*)(tr + slot)     = (ushort4){ f2b(v[0]), f2b(v[1]), f2b(v[2]), f2b(v[3]) };
            *(ushort4*)(tr + slot + 4) = (ushort4){ f2b(v[4]), f2b(v[5]), f2b(v[6]), f2b(v[7]) };
        }
        // ---- prefetch meta(t+2) ----
        int sv2[2]; float ts2;
        {
            int t2 = tile + 2;
            load_meta(mt, t2 < tend ? t2 : tend - 1, E, rbase, g, trow, sv2, ts2);
        }

        __syncthreads();   // A: drains gll(t); publishes te(t), exs(t)=0;
                           //    agg(t-1) hx/exs reads complete

        // ---- issue gll(t+1) -> xs[cur^1]; zero exs(t+1) ----
        if (tile + 1 < tend) {
            #pragma unroll
            for (int i = 0; i < 2; ++i) {
                const int rlo = (rbase + i * 4 + g) & 15;
                const unsigned short* gsrc = xb + (size_t)sv_nxt[i] * IN_CHN + ((c16 ^ rlo) * 8);
                GLL16(gsrc, &xs[cur ^ 1][rbase + i * 4][0]);
            }
        }
        if (tid < TM) exs[cur ^ 1][tid] = 0.0f;

        // ---- MFMA: wave's 32-edge half only (12 ds_read_b128 vs 24) ----
        f32x4 acc[2][2];
        #pragma unroll
        for (int mi = 0; mi < 2; ++mi) {
            acc[mi][0] = (f32x4){0.f, 0.f, 0.f, 0.f};
            acc[mi][1] = (f32x4){0.f, 0.f, 0.f, 0.f};
        }

        __builtin_amdgcn_s_setprio(1);
        const unsigned short* xsc = &xs[cur][0][0];
        const unsigned short* tec = &te[cur][0];
        #pragma unroll
        for (int mi = 0; mi < 2; ++mi) {
            const int r = ebase + mi * 16 + c16;        // r&15 == c16, r&7 == c16&7
            const unsigned short* xrow = xsc + r * 128;
            #pragma unroll
            for (int kk = 0; kk < 4; ++kk) {
                const int slot = ((kk << 2) + g) ^ c16;   // source-swizzled granule
                bf16x8 av = __builtin_bit_cast(bf16x8, *(const uint4*)(xrow + slot * 8));
                acc[mi][0] = __builtin_amdgcn_mfma_f32_16x16x32_bf16(Wf[kk][0], av, acc[mi][0], 0, 0, 0);
                acc[mi][1] = __builtin_amdgcn_mfma_f32_16x16x32_bf16(Wf[kk][1], av, acc[mi][1], 0, 0, 0);
            }
            const unsigned short* trw = tec + r * 64;
            bf16x8 s8 = __builtin_bit_cast(bf16x8, *(const uint4*)(trw + ((g ^ (r & 7)) * 8)));
            bf16x8 c8 = __builtin_bit_cast(bf16x8, *(const uint4*)(trw + (((g + 4) ^ (r & 7)) * 8)));
            acc[mi][0] = __builtin_amdgcn_mfma_f32_16x16x32_bf16(Wf[4][0], s8, acc[mi][0], 0, 0, 0);
            acc[mi][1] = __builtin_amdgcn_mfma_f32_16x16x32_bf16(Wf[4][1], s8, acc[mi][1], 0, 0, 0);
            acc[mi][0] = __builtin_amdgcn_mfma_f32_16x16x32_bf16(Wf[5][0], c8, acc[mi][0], 0, 0, 0);
            acc[mi][1] = __builtin_amdgcn_mfma_f32_16x16x32_bf16(Wf[5][1], c8, acc[mi][1], 0, 0, 0);
        }
        __builtin_amdgcn_s_setprio(0);

        // ---- epilogue: tanh, h -> hx LDS (32ch slice), alpha -> exs[cur] ----
        #pragma unroll
        for (int mi = 0; mi < 2; ++mi) {
            const int r = ebase + mi * 16 + c16;
            float p = 0.0f;
            ushort4 pv[2];
            #pragma unroll
            for (int nf = 0; nf < 2; ++nf) {
                f32x4 z = acc[mi][nf];
                #pragma unroll
                for (int q = 0; q < 4; ++q) {
                    float h = fast_tanh(z[q] + bias_v[nf][q]);
                    z[q] = h;
                    p = fmaf(h, attn_v[nf][q], p);
                }
                pv[nf] = (ushort4){ f2b(z[0]), f2b(z[1]), f2b(z[2]), f2b(z[3]) };
            }
            unsigned short* hp = &hx[r * HXP + cbase + g * 4];
            *(ushort4*)hp        = pv[0];
            *(ushort4*)(hp + 16) = pv[1];
            p += __shfl_xor(p, 16);
            p += __shfl_xor(p, 32);
            if (g == 0) atomicAdd(&exs[cur][r], p);
        }

        LDS_BARRIER();     // C: hx + exs(t) complete; gll(t+1) still in flight

        // ---- aggregation: wave w walks its nodes in [e0, e1) ----
        while (cur_node < Nn) {
            int s  = offs[cur_node];
            if (s >= e1) break;
            int en = offs[cur_node + 1];
            int lo = s > e0 ? s : e0;
            int hi = en < e1 ? en : e1;
            for (int i = lo + sub; i < hi; i += 4) {
                int li = i - e0;
                float ex = __expf(exs[cur][li]);
                uint4 hv = *(const uint4*)&hx[li * HXP + chl * 8];
                den += ex;
                unsigned int hw[4] = { hv.x, hv.y, hv.z, hv.w };
                #pragma unroll
                for (int q = 0; q < 4; ++q) {
                    a[2*q]   = fmaf(ex, b2f((unsigned short)(hw[q] & 0xFFFFu)), a[2*q]);
                    a[2*q+1] = fmaf(ex, b2f((unsigned short)(hw[q] >> 16)),     a[2*q+1]);
                }
            }
            if (en <= e1) {
                // node complete: reduce across subs
                #pragma unroll
                for (int q = 0; q < 8; ++q) {
                    a[q] += __shfl_xor(a[q], 16);
                    a[q] += __shfl_xor(a[q], 32);
                }
                float ds = den + __shfl_xor(den, 16);
                ds += __shfl_xor(ds, 32);
                if (sub == 0) {
                    float* op = out + (size_t)cur_node * OUT_CHN + chl * 8;
                    if (s >= be0) {
                        // interior: sole writer -> store NORMALIZED
                        float rs = __builtin_amdgcn_rcpf(ds + 1e-16f);
                        *(float4*)op       = (float4){a[0]*rs, a[1]*rs, a[2]*rs, a[3]*rs};
                        *(float4*)(op + 4) = (float4){a[4]*rs, a[5]*rs, a[6]*rs, a[7]*rs};
                    } else {
                        // straddle-start: store RAW partial; fixup2 merges+divides
                        *(float4*)op       = (float4){a[0], a[1], a[2], a[3]};
                        *(float4*)(op + 4) = (float4){a[4], a[5], a[6], a[7]};
                        if (chl == 0) den_g[cur_node] = ds;
                    }
                }
                #pragma unroll
                for (int q = 0; q < 8; ++q) a[q] = 0.0f;
                den = 0.0f;
                cur_node += 8;
            } else break;   // carries into next tile
        }

        ts_nxt = ts2;
        sv_nxt[0] = sv2[0]; sv_nxt[1] = sv2[1];
        cur ^= 1;
    }

    // ---- block-end flush: carried straddler -> side buffer (no atomics) ----
    if (cur_node < Nn) {
        int s = offs[cur_node];
        if (s < bend && offs[cur_node + 1] > bend) {
            #pragma unroll
            for (int q = 0; q < 8; ++q) {
                a[q] += __shfl_xor(a[q], 16);
                a[q] += __shfl_xor(a[q], 32);
            }
            float ds = den + __shfl_xor(den, 16);
            ds += __shfl_xor(ds, 32);
            if (sub == 0) {
                float* sv = side_val + (size_t)b * OUT_CHN + chl * 8;
                *(float4*)sv       = (float4){a[0], a[1], a[2], a[3]};
                *(float4*)(sv + 4) = (float4){a[4], a[5], a[6], a[7]};
                if (chl == 0) {
                    side_den[b] = ds;
                    side_node[b] = cur_node;
                }
            }
        }
    }
}

// ---------------- fixup2: merge side partials + divide; zero deg-0 nodes ----

__global__ __launch_bounds__(256) void fixup2(const int* __restrict__ side_node,
    const float* __restrict__ side_den, const float* __restrict__ side_val,
    const int* __restrict__ offs,
    float* __restrict__ out, const float* __restrict__ den_g, int nb, int Nn)
{
    long long gid = (long long)blockIdx.x * 256 + threadIdx.x;
    if (gid < (long long)nb * 64) {
        int w = (int)(gid >> 6);
        int lane = (int)(gid & 63);
        int node = side_node[w];
        if (node < 0) return;
        const float* sv = side_val + (size_t)w * OUT_CHN;
        float* op = out + (size_t)node * OUT_CHN;
        float rs = __builtin_amdgcn_rcpf(den_g[node] + side_den[w] + 1e-16f);
        float2 o = *(float2*)(op + lane * 2);
        float2 s = *(const float2*)(sv + lane * 2);
        o.x = (o.x + s.x) * rs;
        o.y = (o.y + s.y) * rs;
        *(float2*)(op + lane * 2) = o;
    } else {
        int n = (int)(gid - (long long)nb * 64);
        if (n >= Nn) return;
        if (offs[n + 1] == offs[n]) {
            float* op = out + (size_t)n * OUT_CHN;
            for (int c = 0; c < OUT_CHN; c += 4)
                *(float4*)(op + c) = (float4){0, 0, 0, 0};
        }
    }
}

// ---------------- launch ----------------

extern "C" void kernel_launch(void* const* d_in, const int* in_sizes, int n_in,
                              void* d_out, int out_size, void* d_ws, size_t ws_size,
                              hipStream_t stream) {
    const float* x     = (const float*)d_in[0];
    const int*   ei    = (const int*)d_in[1];     // [2, E]
    const float* et    = (const float*)d_in[2];
    const float* freqs = (const float*)d_in[3];
    const float* lw    = (const float*)d_in[4];   // [128, 192]
    const float* lb    = (const float*)d_in[5];
    const float* attn  = (const float*)d_in[6];
    float* out = (float*)d_out;

    const int E  = in_sizes[2];
    const int Nn = in_sizes[0] / IN_CHN;
    const int NB = 512;                            // 2 blocks/CU (LDS-capped)

    // workspace layout
    char* ws = (char*)d_ws;
    uint2* mt      = (uint2*)ws;         size_t off = (size_t)E * sizeof(uint2);
    unsigned short* xb = (unsigned short*)(ws + off); off += (size_t)Nn * IN_CHN * sizeof(unsigned short);
    float* den_g   = (float*)(ws + off); off += (size_t)Nn * sizeof(float);
    int*   deg     = (int*)(ws + off);   off += (size_t)Nn * sizeof(int);
    int*   offs    = (int*)(ws + off);   off += (size_t)(Nn + 1) * sizeof(int);
    int*   cursor  = (int*)(ws + off);   off += (size_t)Nn * sizeof(int);
    int*   partial = (int*)(ws + off);   off += 1024 * sizeof(int);
    int*   side_node = (int*)(ws + off); off += 1024 * sizeof(int);
    float* side_den  = (float*)(ws + off); off += 1024 * sizeof(float);
    float* side_val  = (float*)(ws + off);

    const int nblk = (Nn + 255) / 256;
    const int eblk = (E + 255) / 256;

    hipMemsetAsync(deg, 0, (size_t)Nn * sizeof(int), stream);

    long long n8 = (long long)Nn * IN_CHN / 8;
    long long cgrid = n8 > (long long)E ? n8 : (long long)E;
    cvt_cnt<<<(unsigned)((cgrid + 255) / 256), 256, 0, stream>>>(
        x, xb, ei, deg, side_node, n8, E, NB);

    scan_local<<<nblk, 256, 0, stream>>>(deg, offs, partial, Nn);
    finalize2<<<nblk, 256, 0, stream>>>(offs, partial, cursor, Nn, E, nblk);
    fill_perm<<<eblk, 256, 0, stream>>>(ei, et, cursor, mt, E);

    const int n_tiles = (E + TM - 1) / TM;
    const int kq = n_tiles / NB, kr = n_tiles % NB;
    gemm_fused<<<NB, 512, 0, stream>>>(xb, mt, offs, freqs, lw, lb, attn,
                                       out, den_g, side_node, side_den, side_val,
                                       E, Nn, n_tiles, kq, kr);

    long long fthreads = (long long)NB * 64 + Nn;
    fixup2<<<(unsigned)((fthreads + 255) / 256), 256, 0, stream>>>(
        side_node, side_den, side_val, offs, out, den_g, NB, Nn);
}

// Round 16
// 241.151 us; speedup vs baseline: 1.1080x; 1.1080x over previous
//
#include <hip/hip_runtime.h>
#include <hip/hip_bf16.h>
#include <math.h>

#define IN_CHN 128
#define OUT_CHN 128
#define KD 192
#define TM 64                  // edges per tile
#define HXP 136                // hx row stride in ushorts (272B, 16B-aligned)

typedef __bf16 bf16x8 __attribute__((ext_vector_type(8)));
typedef float f32x4 __attribute__((ext_vector_type(4)));

static __device__ __forceinline__ unsigned short f2b(float f) {
    return __builtin_bit_cast(unsigned short, (__bf16)f);   // RNE
}
static __device__ __forceinline__ float b2f(unsigned short b) {
    return __uint_as_float(((unsigned int)b) << 16);
}
static __device__ __forceinline__ float fast_tanh(float x) {
    float e = __expf(2.0f * x);
    return 1.0f - 2.0f * __builtin_amdgcn_rcpf(e + 1.0f);
}

// async global->LDS, 16B per lane; LDS dest wave-uniform base + lane*16
#define GLL16(gsrc, ldst) \
    __builtin_amdgcn_global_load_lds( \
        (const __attribute__((address_space(1))) unsigned int*)(gsrc), \
        (__attribute__((address_space(3))) unsigned int*)(ldst), 16, 0, 0)

// light barrier: cross-wave LDS visibility WITHOUT draining vmcnt (keeps
// in-flight global_load_lds alive across it)
#define LDS_BARRIER() do { \
    asm volatile("s_waitcnt lgkmcnt(0)" ::: "memory"); \
    __builtin_amdgcn_s_barrier(); \
    __builtin_amdgcn_sched_barrier(0); \
} while (0)

// ---------------- x -> bf16 + degree count + side init (one pass) ----------------
// deg must be zeroed (memsetAsync) before this kernel.

__global__ __launch_bounds__(256) void cvt_cnt(const float* __restrict__ x,
    unsigned short* __restrict__ xb, const int* __restrict__ ei,
    int* __restrict__ deg, int* __restrict__ side_node,
    long long n8, int E, int nb)
{
    long long i = (long long)blockIdx.x * 256 + threadIdx.x;
    if (i < n8) {
        const float4* src = (const float4*)(x + i * 8);
        float4 v0 = src[0], v1 = src[1];
        ushort4 p0 = { f2b(v0.x), f2b(v0.y), f2b(v0.z), f2b(v0.w) };
        ushort4 p1 = { f2b(v1.x), f2b(v1.y), f2b(v1.z), f2b(v1.w) };
        *(ushort4*)(xb + i * 8)     = p0;
        *(ushort4*)(xb + i * 8 + 4) = p1;
    }
    int t = (int)i;
    if (t < E) atomicAdd(&deg[ei[E + t]], 1);
    if (t < nb) side_node[t] = -1;
}

// ---------------- CSR build ----------------

static __device__ __forceinline__ int wave_incl_scan(int v, int lane) {
    #pragma unroll
    for (int off = 1; off < 64; off <<= 1) {
        int t = __shfl_up(v, off);
        if (lane >= off) v += t;
    }
    return v;
}

__global__ __launch_bounds__(256) void scan_local(const int* __restrict__ deg,
    int* __restrict__ offs, int* __restrict__ partial, int Nn)
{
    __shared__ int wsum[4];
    int tid = threadIdx.x, lane = tid & 63, wid = tid >> 6;
    int i = blockIdx.x * 256 + tid;
    int v = (i < Nn) ? deg[i] : 0;
    int incl = wave_incl_scan(v, lane);
    if (lane == 63) wsum[wid] = incl;
    __syncthreads();
    int wpre = 0;
    for (int w = 0; w < wid; ++w) wpre += wsum[w];
    if (i < Nn) offs[i] = wpre + incl - v;
    if (tid == 255) partial[blockIdx.x] = wpre + incl;
}

// per-block: sum partials[0..b) directly (nblk <= 256), add, write cursor
__global__ __launch_bounds__(256) void finalize2(int* __restrict__ offs,
    const int* __restrict__ partial, int* __restrict__ cursor,
    int Nn, int E, int nblk)
{
    __shared__ int wsum[4];
    int b = blockIdx.x, tid = threadIdx.x, lane = tid & 63, wid = tid >> 6;
    int v = (tid < b && tid < nblk) ? partial[tid] : 0;
    #pragma unroll
    for (int off = 32; off > 0; off >>= 1) v += __shfl_xor(v, off);
    if (lane == 0) wsum[wid] = v;
    __syncthreads();
    int bp = wsum[0] + wsum[1] + wsum[2] + wsum[3];
    int i = b * 256 + tid;
    if (i < Nn) {
        int o = offs[i] + bp;
        offs[i] = o; cursor[i] = o;
        if (i == Nn - 1) offs[Nn] = E;   // sentinel
    }
}

// scatter (src, t) into CSR-permuted order as one 8B store
__global__ __launch_bounds__(256) void fill_perm(const int* __restrict__ ei,
    const float* __restrict__ et, int* __restrict__ cursor,
    uint2* __restrict__ mt, int E)
{
    int e = blockIdx.x * 256 + threadIdx.x;
    if (e < E) {
        int d = ei[E + e];
        int pos = atomicAdd(&cursor[d], 1);
        mt[pos] = make_uint2((unsigned)ei[e], __float_as_uint(et[e]));
    }
}

// ---------------- fused MFMA GEMM + softmax aggregation ----------------
// R15's 2x4 wave decomposition (wave = 32 edges x 32 channels; halves the
// MFMA-feed ds_read traffic vs R14's 1x8), PLUS __launch_bounds__(512, 4):
// guarantees unified VGPR+AGPR <= 128/wave -> 4 waves/SIMD -> 2 blocks/CU.
// R15 without the bound silently allocated past 128 -> 1 block/CU -> 22%
// occupancy regression. Schedule (2 barriers), swizzles, staging, agg,
// tail: identical to R14/R15.

__device__ __forceinline__ void load_meta(const uint2* __restrict__ mt,
    int tile, int E, int rbase, int g, int trow, int sv[2], float& tsv)
{
    int e0 = tile * TM;
    #pragma unroll
    for (int i = 0; i < 2; ++i) {
        int e = e0 + rbase + i * 4 + g;
        sv[i] = (int)mt[e < E ? e : E - 1].x;
    }
    int el = e0 + trow;
    tsv = __uint_as_float(mt[el < E ? el : E - 1].y);
}

__global__ __launch_bounds__(512, 4) void gemm_fused(
    const unsigned short* __restrict__ xb, const uint2* __restrict__ mt,
    const int* __restrict__ offs,
    const float* __restrict__ freqs, const float* __restrict__ lw,
    const float* __restrict__ lb, const float* __restrict__ attn,
    float* __restrict__ out, float* __restrict__ den_g,
    int* __restrict__ side_node, float* __restrict__ side_den,
    float* __restrict__ side_val,
    int E, int Nn, int n_tiles, int kq, int kr)
{
    __shared__ unsigned short xs[2][TM][128];   // 32768 B x tile (dbuf)
    __shared__ unsigned short te[2][TM * 64];   // 16384 B te tile (dbuf, swizzled)
    __shared__ unsigned short hx[TM * HXP];     // 17408 B h tile
    __shared__ float exs[2][TM];                //   512 B alpha accumulators (dbuf)

    const int b    = blockIdx.x;
    const int t0   = b * kq + min(b, kr);
    const int cnt  = kq + (b < kr ? 1 : 0);
    if (cnt <= 0 || t0 >= n_tiles) return;
    const int tend = min(t0 + cnt, n_tiles);
    const int be0  = t0 * TM;
    const int bend = min(tend * TM, E);

    const int tid  = threadIdx.x;
    const int lane = tid & 63;
    const int wv   = tid >> 6;          // wave 0..7
    const int c16  = lane & 15;
    const int g    = lane >> 4;         // 0..3
    const int we   = wv & 1;            // edge half: rows [we*32, we*32+32)
    const int wc   = wv >> 1;           // channel quarter: [wc*32, wc*32+32)
    const int cbase = wc * 32;
    const int ebase = we * 32;
    const int rbase = wv * 8;           // gll staging row base (unchanged)
    const int trow  = tid >> 3;         // te row 0..63
    const int tpart = tid & 7;          // te part (0-3 sin, 4-7 cos)
    const int sub  = lane >> 4;         // agg: edge subgroup 0..3
    const int chl  = lane & 15;         // agg: channel lane (8 ch)

    // W frags in registers: lane's row(ch) = cbase + nf*16 + c16; k = kk*32+g*8+j
    bf16x8 Wf[6][2];
    #pragma unroll
    for (int kk = 0; kk < 6; ++kk)
        #pragma unroll
        for (int nf = 0; nf < 2; ++nf) {
            const float* wp = lw + (size_t)(cbase + nf * 16 + c16) * KD + kk * 32 + g * 8;
            float4 v0 = *(const float4*)wp;
            float4 v1 = *(const float4*)(wp + 4);
            bf16x8 bb;
            bb[0] = (__bf16)v0.x; bb[1] = (__bf16)v0.y; bb[2] = (__bf16)v0.z; bb[3] = (__bf16)v0.w;
            bb[4] = (__bf16)v1.x; bb[5] = (__bf16)v1.y; bb[6] = (__bf16)v1.z; bb[7] = (__bf16)v1.w;
            Wf[kk][nf] = bb;
        }
    f32x4 bias_v[2], attn_v[2];
    #pragma unroll
    for (int nf = 0; nf < 2; ++nf) {
        bias_v[nf] = *(const f32x4*)(lb   + cbase + nf * 16 + g * 4);
        attn_v[nf] = *(const f32x4*)(attn + cbase + nf * 16 + g * 4);
    }

    const float coff = (tpart >= 4) ? 1.5707963267948966f : 0.0f;  // cos = sin(x+pi/2)
    float frv[8];
    #pragma unroll
    for (int j = 0; j < 8; ++j) frv[j] = freqs[(tpart & 3) * 8 + j] * 6.283185307179586f;

    // ---- first node of block: binary search offs (uniform across threads) ----
    int n0;
    {
        int lo = 0, hi = Nn;
        while (lo + 1 < hi) {
            int mid = (lo + hi) >> 1;
            if (offs[mid] <= be0) lo = mid; else hi = mid;
        }
        n0 = lo;
    }
    int cur_node = n0 + ((wv - (n0 & 7)) & 7);
    float a[8];
    #pragma unroll
    for (int q = 0; q < 8; ++q) a[q] = 0.0f;
    float den = 0.0f;

    // ---- prologue: meta(t0), gll(t0)->xs[0], te(t0)->te[0], exs[0]=0, meta(t1) ----
    float ts_nxt;
    int sv_nxt[2];
    {
        int sv0[2]; float ts0;
        load_meta(mt, t0, E, rbase, g, trow, sv0, ts0);
        #pragma unroll
        for (int i = 0; i < 2; ++i) {
            const int rlo = (rbase + i * 4 + g) & 15;
            const unsigned short* gsrc = xb + (size_t)sv0[i] * IN_CHN + ((c16 ^ rlo) * 8);
            GLL16(gsrc, &xs[0][rbase + i * 4][0]);
        }
        // te(t0) -> te[0]
        float v[8];
        #pragma unroll
        for (int j = 0; j < 8; ++j)
            v[j] = __sinf(ts0 * frv[j] + coff);
        unsigned short* tr = &te[0][trow * 64];
        int slot = (tpart ^ (trow & 7)) * 8;
        *(ushort4*)(tr + slot)     = (ushort4){ f2b(v[0]), f2b(v[1]), f2b(v[2]), f2b(v[3]) };
        *(ushort4*)(tr + slot + 4) = (ushort4){ f2b(v[4]), f2b(v[5]), f2b(v[6]), f2b(v[7]) };
        if (tid < TM) exs[0][tid] = 0.0f;

        int t1 = t0 + 1;
        load_meta(mt, t1 < tend ? t1 : tend - 1, E, rbase, g, trow, sv_nxt, ts_nxt);
    }

    int cur = 0;
    for (int tile = t0; tile < tend; ++tile) {
        const int e0 = tile * TM;
        const int e1 = e0 + TM;

        // ---- compute + write te(t+1) -> te[cur^1] (pre-A; safe via C(t-1)) ----
        {
            float v[8];
            #pragma unroll
            for (int j = 0; j < 8; ++j)
                v[j] = __sinf(ts_nxt * frv[j] + coff);
            unsigned short* tr = &te[cur ^ 1][trow * 64];
            int slot = (tpart ^ (trow & 7)) * 8;
            *(ushort4*)(tr + slot)     = (ushort4){ f2b(v[0]), f2b(v[1]), f2b(v[2]), f2b(v[3]) };
            *(ushort4*)(tr + slot + 4) = (ushort4){ f2b(v[4]), f2b(v[5]), f2b(v[6]), f2b(v[7]) };
        }
        // ---- prefetch meta(t+2) ----
        int sv2[2]; float ts2;
        {
            int t2 = tile + 2;
            load_meta(mt, t2 < tend ? t2 : tend - 1, E, rbase, g, trow, sv2, ts2);
        }

        __syncthreads();   // A: drains gll(t); publishes te(t), exs(t)=0;
                           //    agg(t-1) hx/exs reads complete

        // ---- issue gll(t+1) -> xs[cur^1]; zero exs(t+1) ----
        if (tile + 1 < tend) {
            #pragma unroll
            for (int i = 0; i < 2; ++i) {
                const int rlo = (rbase + i * 4 + g) & 15;
                const unsigned short* gsrc = xb + (size_t)sv_nxt[i] * IN_CHN + ((c16 ^ rlo) * 8);
                GLL16(gsrc, &xs[cur ^ 1][rbase + i * 4][0]);
            }
        }
        if (tid < TM) exs[cur ^ 1][tid] = 0.0f;

        // ---- MFMA: wave's 32-edge half only (12 ds_read_b128 vs 24) ----
        f32x4 acc[2][2];
        #pragma unroll
        for (int mi = 0; mi < 2; ++mi) {
            acc[mi][0] = (f32x4){0.f, 0.f, 0.f, 0.f};
            acc[mi][1] = (f32x4){0.f, 0.f, 0.f, 0.f};
        }

        __builtin_amdgcn_s_setprio(1);
        const unsigned short* xsc = &xs[cur][0][0];
        const unsigned short* tec = &te[cur][0];
        #pragma unroll
        for (int mi = 0; mi < 2; ++mi) {
            const int r = ebase + mi * 16 + c16;        // r&15 == c16, r&7 == c16&7
            const unsigned short* xrow = xsc + r * 128;
            #pragma unroll
            for (int kk = 0; kk < 4; ++kk) {
                const int slot = ((kk << 2) + g) ^ c16;   // source-swizzled granule
                bf16x8 av = __builtin_bit_cast(bf16x8, *(const uint4*)(xrow + slot * 8));
                acc[mi][0] = __builtin_amdgcn_mfma_f32_16x16x32_bf16(Wf[kk][0], av, acc[mi][0], 0, 0, 0);
                acc[mi][1] = __builtin_amdgcn_mfma_f32_16x16x32_bf16(Wf[kk][1], av, acc[mi][1], 0, 0, 0);
            }
            const unsigned short* trw = tec + r * 64;
            bf16x8 s8 = __builtin_bit_cast(bf16x8, *(const uint4*)(trw + ((g ^ (r & 7)) * 8)));
            bf16x8 c8 = __builtin_bit_cast(bf16x8, *(const uint4*)(trw + (((g + 4) ^ (r & 7)) * 8)));
            acc[mi][0] = __builtin_amdgcn_mfma_f32_16x16x32_bf16(Wf[4][0], s8, acc[mi][0], 0, 0, 0);
            acc[mi][1] = __builtin_amdgcn_mfma_f32_16x16x32_bf16(Wf[4][1], s8, acc[mi][1], 0, 0, 0);
            acc[mi][0] = __builtin_amdgcn_mfma_f32_16x16x32_bf16(Wf[5][0], c8, acc[mi][0], 0, 0, 0);
            acc[mi][1] = __builtin_amdgcn_mfma_f32_16x16x32_bf16(Wf[5][1], c8, acc[mi][1], 0, 0, 0);
        }
        __builtin_amdgcn_s_setprio(0);

        // ---- epilogue: tanh, h -> hx LDS (32ch slice), alpha -> exs[cur] ----
        #pragma unroll
        for (int mi = 0; mi < 2; ++mi) {
            const int r = ebase + mi * 16 + c16;
            float p = 0.0f;
            ushort4 pv[2];
            #pragma unroll
            for (int nf = 0; nf < 2; ++nf) {
                f32x4 z = acc[mi][nf];
                #pragma unroll
                for (int q = 0; q < 4; ++q) {
                    float h = fast_tanh(z[q] + bias_v[nf][q]);
                    z[q] = h;
                    p = fmaf(h, attn_v[nf][q], p);
                }
                pv[nf] = (ushort4){ f2b(z[0]), f2b(z[1]), f2b(z[2]), f2b(z[3]) };
            }
            unsigned short* hp = &hx[r * HXP + cbase + g * 4];
            *(ushort4*)hp        = pv[0];
            *(ushort4*)(hp + 16) = pv[1];
            p += __shfl_xor(p, 16);
            p += __shfl_xor(p, 32);
            if (g == 0) atomicAdd(&exs[cur][r], p);
        }

        LDS_BARRIER();     // C: hx + exs(t) complete; gll(t+1) still in flight

        // ---- aggregation: wave w walks its nodes in [e0, e1) ----
        while (cur_node < Nn) {
            int s  = offs[cur_node];
            if (s >= e1) break;
            int en = offs[cur_node + 1];
            int lo = s > e0 ? s : e0;
            int hi = en < e1 ? en : e1;
            for (int i = lo + sub; i < hi; i += 4) {
                int li = i - e0;
                float ex = __expf(exs[cur][li]);
                uint4 hv = *(const uint4*)&hx[li * HXP + chl * 8];
                den += ex;
                unsigned int hw[4] = { hv.x, hv.y, hv.z, hv.w };
                #pragma unroll
                for (int q = 0; q < 4; ++q) {
                    a[2*q]   = fmaf(ex, b2f((unsigned short)(hw[q] & 0xFFFFu)), a[2*q]);
                    a[2*q+1] = fmaf(ex, b2f((unsigned short)(hw[q] >> 16)),     a[2*q+1]);
                }
            }
            if (en <= e1) {
                // node complete: reduce across subs
                #pragma unroll
                for (int q = 0; q < 8; ++q) {
                    a[q] += __shfl_xor(a[q], 16);
                    a[q] += __shfl_xor(a[q], 32);
                }
                float ds = den + __shfl_xor(den, 16);
                ds += __shfl_xor(ds, 32);
                if (sub == 0) {
                    float* op = out + (size_t)cur_node * OUT_CHN + chl * 8;
                    if (s >= be0) {
                        // interior: sole writer -> store NORMALIZED
                        float rs = __builtin_amdgcn_rcpf(ds + 1e-16f);
                        *(float4*)op       = (float4){a[0]*rs, a[1]*rs, a[2]*rs, a[3]*rs};
                        *(float4*)(op + 4) = (float4){a[4]*rs, a[5]*rs, a[6]*rs, a[7]*rs};
                    } else {
                        // straddle-start: store RAW partial; fixup2 merges+divides
                        *(float4*)op       = (float4){a[0], a[1], a[2], a[3]};
                        *(float4*)(op + 4) = (float4){a[4], a[5], a[6], a[7]};
                        if (chl == 0) den_g[cur_node] = ds;
                    }
                }
                #pragma unroll
                for (int q = 0; q < 8; ++q) a[q] = 0.0f;
                den = 0.0f;
                cur_node += 8;
            } else break;   // carries into next tile
        }

        ts_nxt = ts2;
        sv_nxt[0] = sv2[0]; sv_nxt[1] = sv2[1];
        cur ^= 1;
    }

    // ---- block-end flush: carried straddler -> side buffer (no atomics) ----
    if (cur_node < Nn) {
        int s = offs[cur_node];
        if (s < bend && offs[cur_node + 1] > bend) {
            #pragma unroll
            for (int q = 0; q < 8; ++q) {
                a[q] += __shfl_xor(a[q], 16);
                a[q] += __shfl_xor(a[q], 32);
            }
            float ds = den + __shfl_xor(den, 16);
            ds += __shfl_xor(ds, 32);
            if (sub == 0) {
                float* sv = side_val + (size_t)b * OUT_CHN + chl * 8;
                *(float4*)sv       = (float4){a[0], a[1], a[2], a[3]};
                *(float4*)(sv + 4) = (float4){a[4], a[5], a[6], a[7]};
                if (chl == 0) {
                    side_den[b] = ds;
                    side_node[b] = cur_node;
                }
            }
        }
    }
}

// ---------------- fixup2: merge side partials + divide; zero deg-0 nodes ----

__global__ __launch_bounds__(256) void fixup2(const int* __restrict__ side_node,
    const float* __restrict__ side_den, const float* __restrict__ side_val,
    const int* __restrict__ offs,
    float* __restrict__ out, const float* __restrict__ den_g, int nb, int Nn)
{
    long long gid = (long long)blockIdx.x * 256 + threadIdx.x;
    if (gid < (long long)nb * 64) {
        int w = (int)(gid >> 6);
        int lane = (int)(gid & 63);
        int node = side_node[w];
        if (node < 0) return;
        const float* sv = side_val + (size_t)w * OUT_CHN;
        float* op = out + (size_t)node * OUT_CHN;
        float rs = __builtin_amdgcn_rcpf(den_g[node] + side_den[w] + 1e-16f);
        float2 o = *(float2*)(op + lane * 2);
        float2 s = *(const float2*)(sv + lane * 2);
        o.x = (o.x + s.x) * rs;
        o.y = (o.y + s.y) * rs;
        *(float2*)(op + lane * 2) = o;
    } else {
        int n = (int)(gid - (long long)nb * 64);
        if (n >= Nn) return;
        if (offs[n + 1] == offs[n]) {
            float* op = out + (size_t)n * OUT_CHN;
            for (int c = 0; c < OUT_CHN; c += 4)
                *(float4*)(op + c) = (float4){0, 0, 0, 0};
        }
    }
}

// ---------------- launch ----------------

extern "C" void kernel_launch(void* const* d_in, const int* in_sizes, int n_in,
                              void* d_out, int out_size, void* d_ws, size_t ws_size,
                              hipStream_t stream) {
    const float* x     = (const float*)d_in[0];
    const int*   ei    = (const int*)d_in[1];     // [2, E]
    const float* et    = (const float*)d_in[2];
    const float* freqs = (const float*)d_in[3];
    const float* lw    = (const float*)d_in[4];   // [128, 192]
    const float* lb    = (const float*)d_in[5];
    const float* attn  = (const float*)d_in[6];
    float* out = (float*)d_out;

    const int E  = in_sizes[2];
    const int Nn = in_sizes[0] / IN_CHN;
    const int NB = 512;                            // 2 blocks/CU (LDS-capped)

    // workspace layout
    char* ws = (char*)d_ws;
    uint2* mt      = (uint2*)ws;         size_t off = (size_t)E * sizeof(uint2);
    unsigned short* xb = (unsigned short*)(ws + off); off += (size_t)Nn * IN_CHN * sizeof(unsigned short);
    float* den_g   = (float*)(ws + off); off += (size_t)Nn * sizeof(float);
    int*   deg     = (int*)(ws + off);   off += (size_t)Nn * sizeof(int);
    int*   offs    = (int*)(ws + off);   off += (size_t)(Nn + 1) * sizeof(int);
    int*   cursor  = (int*)(ws + off);   off += (size_t)Nn * sizeof(int);
    int*   partial = (int*)(ws + off);   off += 1024 * sizeof(int);
    int*   side_node = (int*)(ws + off); off += 1024 * sizeof(int);
    float* side_den  = (float*)(ws + off); off += 1024 * sizeof(float);
    float* side_val  = (float*)(ws + off);

    const int nblk = (Nn + 255) / 256;
    const int eblk = (E + 255) / 256;

    hipMemsetAsync(deg, 0, (size_t)Nn * sizeof(int), stream);

    long long n8 = (long long)Nn * IN_CHN / 8;
    long long cgrid = n8 > (long long)E ? n8 : (long long)E;
    cvt_cnt<<<(unsigned)((cgrid + 255) / 256), 256, 0, stream>>>(
        x, xb, ei, deg, side_node, n8, E, NB);

    scan_local<<<nblk, 256, 0, stream>>>(deg, offs, partial, Nn);
    finalize2<<<nblk, 256, 0, stream>>>(offs, partial, cursor, Nn, E, nblk);
    fill_perm<<<eblk, 256, 0, stream>>>(ei, et, cursor, mt, E);

    const int n_tiles = (E + TM - 1) / TM;
    const int kq = n_tiles / NB, kr = n_tiles % NB;
    gemm_fused<<<NB, 512, 0, stream>>>(xb, mt, offs, freqs, lw, lb, attn,
                                       out, den_g, side_node, side_den, side_val,
                                       E, Nn, n_tiles, kq, kr);

    long long fthreads = (long long)NB * 64 + Nn;
    fixup2<<<(unsigned)((fthreads + 255) / 256), 256, 0, stream>>>(
        side_node, side_den, side_val, offs, out, den_g, NB, Nn);
}

// Round 17
// 227.201 us; speedup vs baseline: 1.1760x; 1.0614x over previous
//
#include <hip/hip_runtime.h>
#include <hip/hip_bf16.h>
#include <math.h>

#define IN_CHN 128
#define OUT_CHN 128
#define KD 192
#define TM 64                  // edges per tile
#define HXP 136                // hx row stride in ushorts (272B, 16B-aligned)

typedef __bf16 bf16x8 __attribute__((ext_vector_type(8)));
typedef float f32x4 __attribute__((ext_vector_type(4)));

static __device__ __forceinline__ unsigned short f2b(float f) {
    return __builtin_bit_cast(unsigned short, (__bf16)f);   // RNE
}
static __device__ __forceinline__ float b2f(unsigned short b) {
    return __uint_as_float(((unsigned int)b) << 16);
}
static __device__ __forceinline__ float fast_tanh(float x) {
    float e = __expf(2.0f * x);
    return 1.0f - 2.0f * __builtin_amdgcn_rcpf(e + 1.0f);
}

// async global->LDS, 16B per lane; LDS dest wave-uniform base + lane*16
#define GLL16(gsrc, ldst) \
    __builtin_amdgcn_global_load_lds( \
        (const __attribute__((address_space(1))) unsigned int*)(gsrc), \
        (__attribute__((address_space(3))) unsigned int*)(ldst), 16, 0, 0)

// light barrier: cross-wave LDS visibility WITHOUT draining vmcnt (keeps
// in-flight global_load_lds + prefetches alive across it)
#define LDS_BARRIER() do { \
    asm volatile("s_waitcnt lgkmcnt(0)" ::: "memory"); \
    __builtin_amdgcn_s_barrier(); \
    __builtin_amdgcn_sched_barrier(0); \
} while (0)

// ---------------- x -> bf16 + degree count + side init (one pass) ----------------
// deg must be zeroed (memsetAsync) before this kernel.

__global__ __launch_bounds__(256) void cvt_cnt(const float* __restrict__ x,
    unsigned short* __restrict__ xb, const int* __restrict__ ei,
    int* __restrict__ deg, int* __restrict__ side_node,
    long long n8, int E, int nb)
{
    long long i = (long long)blockIdx.x * 256 + threadIdx.x;
    if (i < n8) {
        const float4* src = (const float4*)(x + i * 8);
        float4 v0 = src[0], v1 = src[1];
        ushort4 p0 = { f2b(v0.x), f2b(v0.y), f2b(v0.z), f2b(v0.w) };
        ushort4 p1 = { f2b(v1.x), f2b(v1.y), f2b(v1.z), f2b(v1.w) };
        *(ushort4*)(xb + i * 8)     = p0;
        *(ushort4*)(xb + i * 8 + 4) = p1;
    }
    int t = (int)i;
    if (t < E) atomicAdd(&deg[ei[E + t]], 1);
    if (t < nb) side_node[t] = -1;
}

// ---------------- CSR build ----------------

static __device__ __forceinline__ int wave_incl_scan(int v, int lane) {
    #pragma unroll
    for (int off = 1; off < 64; off <<= 1) {
        int t = __shfl_up(v, off);
        if (lane >= off) v += t;
    }
    return v;
}

__global__ __launch_bounds__(256) void scan_local(const int* __restrict__ deg,
    int* __restrict__ offs, int* __restrict__ partial, int Nn)
{
    __shared__ int wsum[4];
    int tid = threadIdx.x, lane = tid & 63, wid = tid >> 6;
    int i = blockIdx.x * 256 + tid;
    int v = (i < Nn) ? deg[i] : 0;
    int incl = wave_incl_scan(v, lane);
    if (lane == 63) wsum[wid] = incl;
    __syncthreads();
    int wpre = 0;
    for (int w = 0; w < wid; ++w) wpre += wsum[w];
    if (i < Nn) offs[i] = wpre + incl - v;
    if (tid == 255) partial[blockIdx.x] = wpre + incl;
}

// per-block: sum partials[0..b) directly (nblk <= 256), add, write cursor
__global__ __launch_bounds__(256) void finalize2(int* __restrict__ offs,
    const int* __restrict__ partial, int* __restrict__ cursor,
    int Nn, int E, int nblk)
{
    __shared__ int wsum[4];
    int b = blockIdx.x, tid = threadIdx.x, lane = tid & 63, wid = tid >> 6;
    int v = (tid < b && tid < nblk) ? partial[tid] : 0;
    #pragma unroll
    for (int off = 32; off > 0; off >>= 1) v += __shfl_xor(v, off);
    if (lane == 0) wsum[wid] = v;
    __syncthreads();
    int bp = wsum[0] + wsum[1] + wsum[2] + wsum[3];
    int i = b * 256 + tid;
    if (i < Nn) {
        int o = offs[i] + bp;
        offs[i] = o; cursor[i] = o;
        if (i == Nn - 1) offs[Nn] = E;   // sentinel
    }
}

// scatter (src, t) into CSR-permuted order as one 8B store
__global__ __launch_bounds__(256) void fill_perm(const int* __restrict__ ei,
    const float* __restrict__ et, int* __restrict__ cursor,
    uint2* __restrict__ mt, int E)
{
    int e = blockIdx.x * 256 + threadIdx.x;
    if (e < E) {
        int d = ei[E + e];
        int pos = atomicAdd(&cursor[d], 1);
        mt[pos] = make_uint2((unsigned)ei[e], __float_as_uint(et[e]));
    }
}

// ---------------- fused MFMA GEMM + softmax aggregation ----------------
// R14's proven structure (1x8 wave decomposition, 2-barrier schedule,
// in-kernel normalization). R17 deltas:
//  (1) meta(t+2) prefetch moved AFTER barrier A -> it is no longer drained
//      by A's implicit vmcnt(0) in the same tile it was issued (was ~150-200
//      exposed cycles/tile); now drains at A(t+1), a full tile later.
//  (2) s_setprio removed (lockstep barrier-synced waves; m190 regime).
// LDS = 32K xs-dbuf + 16K te-dbuf + 17K hx + 0.5K exs = 67072 B -> 2 blk/CU.

__device__ __forceinline__ void load_meta(const uint2* __restrict__ mt,
    int tile, int E, int rbase, int g, int trow, int sv[2], float& tsv)
{
    int e0 = tile * TM;
    #pragma unroll
    for (int i = 0; i < 2; ++i) {
        int e = e0 + rbase + i * 4 + g;
        sv[i] = (int)mt[e < E ? e : E - 1].x;
    }
    int el = e0 + trow;
    tsv = __uint_as_float(mt[el < E ? el : E - 1].y);
}

__global__ __launch_bounds__(512) void gemm_fused(
    const unsigned short* __restrict__ xb, const uint2* __restrict__ mt,
    const int* __restrict__ offs,
    const float* __restrict__ freqs, const float* __restrict__ lw,
    const float* __restrict__ lb, const float* __restrict__ attn,
    float* __restrict__ out, float* __restrict__ den_g,
    int* __restrict__ side_node, float* __restrict__ side_den,
    float* __restrict__ side_val,
    int E, int Nn, int n_tiles, int kq, int kr)
{
    __shared__ unsigned short xs[2][TM][128];   // 32768 B x tile (dbuf)
    __shared__ unsigned short te[2][TM * 64];   // 16384 B te tile (dbuf, swizzled)
    __shared__ unsigned short hx[TM * HXP];     // 17408 B h tile
    __shared__ float exs[2][TM];                //   512 B alpha accumulators (dbuf)

    const int b    = blockIdx.x;
    const int t0   = b * kq + min(b, kr);
    const int cnt  = kq + (b < kr ? 1 : 0);
    if (cnt <= 0 || t0 >= n_tiles) return;
    const int tend = min(t0 + cnt, n_tiles);
    const int be0  = t0 * TM;
    const int bend = min(tend * TM, E);

    const int tid  = threadIdx.x;
    const int lane = tid & 63;
    const int wv   = tid >> 6;          // wave 0..7
    const int c16  = lane & 15;
    const int g    = lane >> 4;         // 0..3
    const int wbase = wv * 16;          // this wave's channel base
    const int rbase = wv * 8;           // this wave's gll row base
    const int trow  = tid >> 3;         // te row 0..63
    const int tpart = tid & 7;          // te part (0-3 sin, 4-7 cos)
    const int sub  = lane >> 4;         // agg: edge subgroup 0..3
    const int chl  = lane & 15;         // agg: channel lane (8 ch)

    // W frags in registers: lane's row(ch) = wbase+c16; k = kk*32+g*8+j
    bf16x8 Wf[6];
    #pragma unroll
    for (int kk = 0; kk < 6; ++kk) {
        const float* wp = lw + (size_t)(wbase + c16) * KD + kk * 32 + g * 8;
        float4 v0 = *(const float4*)wp;
        float4 v1 = *(const float4*)(wp + 4);
        bf16x8 bb;
        bb[0] = (__bf16)v0.x; bb[1] = (__bf16)v0.y; bb[2] = (__bf16)v0.z; bb[3] = (__bf16)v0.w;
        bb[4] = (__bf16)v1.x; bb[5] = (__bf16)v1.y; bb[6] = (__bf16)v1.z; bb[7] = (__bf16)v1.w;
        Wf[kk] = bb;
    }
    const f32x4 bias_v = *(const f32x4*)(lb   + wbase + g * 4);
    const f32x4 attn_v = *(const f32x4*)(attn + wbase + g * 4);

    const float coff = (tpart >= 4) ? 1.5707963267948966f : 0.0f;  // cos = sin(x+pi/2)
    float frv[8];
    #pragma unroll
    for (int j = 0; j < 8; ++j) frv[j] = freqs[(tpart & 3) * 8 + j] * 6.283185307179586f;

    // ---- first node of block: binary search offs (uniform across threads) ----
    int n0;
    {
        int lo = 0, hi = Nn;
        while (lo + 1 < hi) {
            int mid = (lo + hi) >> 1;
            if (offs[mid] <= be0) lo = mid; else hi = mid;
        }
        n0 = lo;
    }
    int cur_node = n0 + ((wv - (n0 & 7)) & 7);
    float a[8];
    #pragma unroll
    for (int q = 0; q < 8; ++q) a[q] = 0.0f;
    float den = 0.0f;

    // ---- prologue: meta(t0), gll(t0)->xs[0], te(t0)->te[0], exs[0]=0, meta(t1) ----
    float ts_nxt;
    int sv_nxt[2];
    {
        int sv0[2]; float ts0;
        load_meta(mt, t0, E, rbase, g, trow, sv0, ts0);
        #pragma unroll
        for (int i = 0; i < 2; ++i) {
            const int rlo = (rbase + i * 4 + g) & 15;
            const unsigned short* gsrc = xb + (size_t)sv0[i] * IN_CHN + ((c16 ^ rlo) * 8);
            GLL16(gsrc, &xs[0][rbase + i * 4][0]);
        }
        // te(t0) -> te[0]
        float v[8];
        #pragma unroll
        for (int j = 0; j < 8; ++j)
            v[j] = __sinf(ts0 * frv[j] + coff);
        unsigned short* tr = &te[0][trow * 64];
        int slot = (tpart ^ (trow & 7)) * 8;
        *(ushort4*)(tr + slot)     = (ushort4){ f2b(v[0]), f2b(v[1]), f2b(v[2]), f2b(v[3]) };
        *(ushort4*)(tr + slot + 4) = (ushort4){ f2b(v[4]), f2b(v[5]), f2b(v[6]), f2b(v[7]) };
        if (tid < TM) exs[0][tid] = 0.0f;

        int t1 = t0 + 1;
        load_meta(mt, t1 < tend ? t1 : tend - 1, E, rbase, g, trow, sv_nxt, ts_nxt);
    }

    int cur = 0;
    for (int tile = t0; tile < tend; ++tile) {
        const int e0 = tile * TM;
        const int e1 = e0 + TM;

        // ---- compute + write te(t+1) -> te[cur^1] (pre-A; safe via C(t-1)) ----
        {
            float v[8];
            #pragma unroll
            for (int j = 0; j < 8; ++j)
                v[j] = __sinf(ts_nxt * frv[j] + coff);
            unsigned short* tr = &te[cur ^ 1][trow * 64];
            int slot = (tpart ^ (trow & 7)) * 8;
            *(ushort4*)(tr + slot)     = (ushort4){ f2b(v[0]), f2b(v[1]), f2b(v[2]), f2b(v[3]) };
            *(ushort4*)(tr + slot + 4) = (ushort4){ f2b(v[4]), f2b(v[5]), f2b(v[6]), f2b(v[7]) };
        }

        __syncthreads();   // A: drains gll(t); publishes te(t), exs(t)=0;
                           //    agg(t-1) hx/exs reads complete

        // ---- issue gll(t+1) -> xs[cur^1]; zero exs(t+1) ----
        if (tile + 1 < tend) {
            #pragma unroll
            for (int i = 0; i < 2; ++i) {
                const int rlo = (rbase + i * 4 + g) & 15;
                const unsigned short* gsrc = xb + (size_t)sv_nxt[i] * IN_CHN + ((c16 ^ rlo) * 8);
                GLL16(gsrc, &xs[cur ^ 1][rbase + i * 4][0]);
            }
        }
        if (tid < TM) exs[cur ^ 1][tid] = 0.0f;

        // ---- prefetch meta(t+2) POST-A: not drained until A(t+1) ----
        int sv2[2]; float ts2;
        {
            int t2 = tile + 2;
            load_meta(mt, t2 < tend ? t2 : tend - 1, E, rbase, g, trow, sv2, ts2);
        }

        // ---- MFMA: x frags from swizzled LDS, te frags from LDS ----
        f32x4 acc[4];
        #pragma unroll
        for (int mi = 0; mi < 4; ++mi) acc[mi] = (f32x4){0.f, 0.f, 0.f, 0.f};

        const unsigned short* xsc = &xs[cur][0][0];
        const unsigned short* tec = &te[cur][0];
        #pragma unroll
        for (int mi = 0; mi < 4; ++mi) {
            const int r = mi * 16 + c16;
            const unsigned short* xrow = xsc + r * 128;
            #pragma unroll
            for (int kk = 0; kk < 4; ++kk) {
                const int slot = ((kk << 2) + g) ^ c16;   // source-swizzled granule
                bf16x8 av = __builtin_bit_cast(bf16x8, *(const uint4*)(xrow + slot * 8));
                acc[mi] = __builtin_amdgcn_mfma_f32_16x16x32_bf16(Wf[kk], av, acc[mi], 0, 0, 0);
            }
            const unsigned short* trw = tec + r * 64;
            bf16x8 s8 = __builtin_bit_cast(bf16x8, *(const uint4*)(trw + ((g ^ (r & 7)) * 8)));
            bf16x8 c8 = __builtin_bit_cast(bf16x8, *(const uint4*)(trw + (((g + 4) ^ (r & 7)) * 8)));
            acc[mi] = __builtin_amdgcn_mfma_f32_16x16x32_bf16(Wf[4], s8, acc[mi], 0, 0, 0);
            acc[mi] = __builtin_amdgcn_mfma_f32_16x16x32_bf16(Wf[5], c8, acc[mi], 0, 0, 0);
        }

        // ---- epilogue: tanh, h -> hx LDS, alpha -> exs[cur] (LDS atomic) ----
        #pragma unroll
        for (int mi = 0; mi < 4; ++mi) {
            const int r = mi * 16 + c16;
            f32x4 z = acc[mi];
            float p = 0.0f;
            #pragma unroll
            for (int q = 0; q < 4; ++q) {
                float h = fast_tanh(z[q] + bias_v[q]);
                z[q] = h;
                p = fmaf(h, attn_v[q], p);
            }
            ushort4 pv = (ushort4){ f2b(z[0]), f2b(z[1]), f2b(z[2]), f2b(z[3]) };
            *(ushort4*)&hx[r * HXP + wbase + g * 4] = pv;
            p += __shfl_xor(p, 16);
            p += __shfl_xor(p, 32);
            if (g == 0) atomicAdd(&exs[cur][r], p);
        }

        LDS_BARRIER();     // C: hx + exs(t) complete; gll(t+1) + meta(t+2) in flight

        // ---- aggregation: wave w walks its nodes in [e0, e1) ----
        while (cur_node < Nn) {
            int s  = offs[cur_node];
            if (s >= e1) break;
            int en = offs[cur_node + 1];
            int lo = s > e0 ? s : e0;
            int hi = en < e1 ? en : e1;
            for (int i = lo + sub; i < hi; i += 4) {
                int li = i - e0;
                float ex = __expf(exs[cur][li]);
                uint4 hv = *(const uint4*)&hx[li * HXP + chl * 8];
                den += ex;
                unsigned int hw[4] = { hv.x, hv.y, hv.z, hv.w };
                #pragma unroll
                for (int q = 0; q < 4; ++q) {
                    a[2*q]   = fmaf(ex, b2f((unsigned short)(hw[q] & 0xFFFFu)), a[2*q]);
                    a[2*q+1] = fmaf(ex, b2f((unsigned short)(hw[q] >> 16)),     a[2*q+1]);
                }
            }
            if (en <= e1) {
                // node complete: reduce across subs
                #pragma unroll
                for (int q = 0; q < 8; ++q) {
                    a[q] += __shfl_xor(a[q], 16);
                    a[q] += __shfl_xor(a[q], 32);
                }
                float ds = den + __shfl_xor(den, 16);
                ds += __shfl_xor(ds, 32);
                if (sub == 0) {
                    float* op = out + (size_t)cur_node * OUT_CHN + chl * 8;
                    if (s >= be0) {
                        // interior: sole writer -> store NORMALIZED
                        float rs = __builtin_amdgcn_rcpf(ds + 1e-16f);
                        *(float4*)op       = (float4){a[0]*rs, a[1]*rs, a[2]*rs, a[3]*rs};
                        *(float4*)(op + 4) = (float4){a[4]*rs, a[5]*rs, a[6]*rs, a[7]*rs};
                    } else {
                        // straddle-start: store RAW partial; fixup2 merges+divides
                        *(float4*)op       = (float4){a[0], a[1], a[2], a[3]};
                        *(float4*)(op + 4) = (float4){a[4], a[5], a[6], a[7]};
                        if (chl == 0) den_g[cur_node] = ds;
                    }
                }
                #pragma unroll
                for (int q = 0; q < 8; ++q) a[q] = 0.0f;
                den = 0.0f;
                cur_node += 8;
            } else break;   // carries into next tile
        }

        ts_nxt = ts2;
        sv_nxt[0] = sv2[0]; sv_nxt[1] = sv2[1];
        cur ^= 1;
    }

    // ---- block-end flush: carried straddler -> side buffer (no atomics) ----
    if (cur_node < Nn) {
        int s = offs[cur_node];
        if (s < bend && offs[cur_node + 1] > bend) {
            #pragma unroll
            for (int q = 0; q < 8; ++q) {
                a[q] += __shfl_xor(a[q], 16);
                a[q] += __shfl_xor(a[q], 32);
            }
            float ds = den + __shfl_xor(den, 16);
            ds += __shfl_xor(ds, 32);
            if (sub == 0) {
                float* sv = side_val + (size_t)b * OUT_CHN + chl * 8;
                *(float4*)sv       = (float4){a[0], a[1], a[2], a[3]};
                *(float4*)(sv + 4) = (float4){a[4], a[5], a[6], a[7]};
                if (chl == 0) {
                    side_den[b] = ds;
                    side_node[b] = cur_node;
                }
            }
        }
    }
}

// ---------------- fixup2: merge side partials + divide; zero deg-0 nodes ----

__global__ __launch_bounds__(256) void fixup2(const int* __restrict__ side_node,
    const float* __restrict__ side_den, const float* __restrict__ side_val,
    const int* __restrict__ offs,
    float* __restrict__ out, const float* __restrict__ den_g, int nb, int Nn)
{
    long long gid = (long long)blockIdx.x * 256 + threadIdx.x;
    if (gid < (long long)nb * 64) {
        int w = (int)(gid >> 6);
        int lane = (int)(gid & 63);
        int node = side_node[w];
        if (node < 0) return;
        const float* sv = side_val + (size_t)w * OUT_CHN;
        float* op = out + (size_t)node * OUT_CHN;
        float rs = __builtin_amdgcn_rcpf(den_g[node] + side_den[w] + 1e-16f);
        float2 o = *(float2*)(op + lane * 2);
        float2 s = *(const float2*)(sv + lane * 2);
        o.x = (o.x + s.x) * rs;
        o.y = (o.y + s.y) * rs;
        *(float2*)(op + lane * 2) = o;
    } else {
        int n = (int)(gid - (long long)nb * 64);
        if (n >= Nn) return;
        if (offs[n + 1] == offs[n]) {
            float* op = out + (size_t)n * OUT_CHN;
            for (int c = 0; c < OUT_CHN; c += 4)
                *(float4*)(op + c) = (float4){0, 0, 0, 0};
        }
    }
}

// ---------------- launch ----------------

extern "C" void kernel_launch(void* const* d_in, const int* in_sizes, int n_in,
                              void* d_out, int out_size, void* d_ws, size_t ws_size,
                              hipStream_t stream) {
    const float* x     = (const float*)d_in[0];
    const int*   ei    = (const int*)d_in[1];     // [2, E]
    const float* et    = (const float*)d_in[2];
    const float* freqs = (const float*)d_in[3];
    const float* lw    = (const float*)d_in[4];   // [128, 192]
    const float* lb    = (const float*)d_in[5];
    const float* attn  = (const float*)d_in[6];
    float* out = (float*)d_out;

    const int E  = in_sizes[2];
    const int Nn = in_sizes[0] / IN_CHN;
    const int NB = 512;                            // 2 blocks/CU (LDS-capped)

    // workspace layout
    char* ws = (char*)d_ws;
    uint2* mt      = (uint2*)ws;         size_t off = (size_t)E * sizeof(uint2);
    unsigned short* xb = (unsigned short*)(ws + off); off += (size_t)Nn * IN_CHN * sizeof(unsigned short);
    float* den_g   = (float*)(ws + off); off += (size_t)Nn * sizeof(float);
    int*   deg     = (int*)(ws + off);   off += (size_t)Nn * sizeof(int);
    int*   offs    = (int*)(ws + off);   off += (size_t)(Nn + 1) * sizeof(int);
    int*   cursor  = (int*)(ws + off);   off += (size_t)Nn * sizeof(int);
    int*   partial = (int*)(ws + off);   off += 1024 * sizeof(int);
    int*   side_node = (int*)(ws + off); off += 1024 * sizeof(int);
    float* side_den  = (float*)(ws + off); off += 1024 * sizeof(float);
    float* side_val  = (float*)(ws + off);

    const int nblk = (Nn + 255) / 256;
    const int eblk = (E + 255) / 256;

    hipMemsetAsync(deg, 0, (size_t)Nn * sizeof(int), stream);

    long long n8 = (long long)Nn * IN_CHN / 8;
    long long cgrid = n8 > (long long)E ? n8 : (long long)E;
    cvt_cnt<<<(unsigned)((cgrid + 255) / 256), 256, 0, stream>>>(
        x, xb, ei, deg, side_node, n8, E, NB);

    scan_local<<<nblk, 256, 0, stream>>>(deg, offs, partial, Nn);
    finalize2<<<nblk, 256, 0, stream>>>(offs, partial, cursor, Nn, E, nblk);
    fill_perm<<<eblk, 256, 0, stream>>>(ei, et, cursor, mt, E);

    const int n_tiles = (E + TM - 1) / TM;
    const int kq = n_tiles / NB, kr = n_tiles % NB;
    gemm_fused<<<NB, 512, 0, stream>>>(xb, mt, offs, freqs, lw, lb, attn,
                                       out, den_g, side_node, side_den, side_val,
                                       E, Nn, n_tiles, kq, kr);

    long long fthreads = (long long)NB * 64 + Nn;
    fixup2<<<(unsigned)((fthreads + 255) / 256), 256, 0, stream>>>(
        side_node, side_den, side_val, offs, out, den_g, NB, Nn);
}